// Round 14
// baseline (444.343 us; speedup 1.0000x reference)
//
#include <hip/hip_runtime.h>
#include <hip/hip_bf16.h>
#include <cstdint>

typedef __attribute__((ext_vector_type(8))) short bf16x8;
typedef __attribute__((ext_vector_type(4))) float f32x4;
typedef __attribute__((ext_vector_type(4))) int   i32x4;
typedef __attribute__((ext_vector_type(16))) int  i32x16;

static constexpr int Mdim = 8192;
static constexpr int Kdim = 4096;
static constexpr int Ndim = 4096;
static constexpr int BM = 256, BN = 256;   // 256^2 tile
static constexpr int BKB = 64;             // K-bytes per tile (i8 => 64 k-elems)
static constexpr int NKT = Kdim / BKB;     // 64 K-tiles
static constexpr int TILEB = BM * BKB;     // 16 KB per matrix per buffer

static constexpr int QBLOCKS = Mdim / 4;                      // 2048: quant role
static constexpr int SBLOCKS = (Kdim / 64) * (Ndim / 64);     // 4096: sign role

__device__ __forceinline__ void async_copy16(const void* g, void* l) {
  __builtin_amdgcn_global_load_lds(
      (const __attribute__((address_space(1))) void*)g,
      (__attribute__((address_space(3))) void*)l, 16, 0, 0);
}

// ---- fused prepass (MEASURED R9: < 159 us, not in top-5; neutral vs split.
//      FROZEN — not the dominant term). blocks [0,QBLOCKS) quantize x;
//      blocks [QBLOCKS,+SBLOCKS) sign+transpose w.
__global__ __launch_bounds__(256) void prep_kernel(const float* __restrict__ x,
                                                   int8_t* __restrict__ xq,
                                                   float* __restrict__ srow,
                                                   const float* __restrict__ w,
                                                   int8_t* __restrict__ wsT) {
  const int tid = threadIdx.x;
  if (blockIdx.x < QBLOCKS) {
    const int wv  = tid >> 6;
    const int l   = tid & 63;
    const int row = blockIdx.x * 4 + wv;
    const float* xr = x + (size_t)row * Kdim;
    float4 v[16];
    float m = 0.f;
    #pragma unroll
    for (int j = 0; j < 16; ++j) {
      v[j] = *reinterpret_cast<const float4*>(xr + (size_t)(j * 64 + l) * 4);
      m = fmaxf(m, fmaxf(fmaxf(fabsf(v[j].x), fabsf(v[j].y)),
                         fmaxf(fabsf(v[j].z), fabsf(v[j].w))));
    }
    #pragma unroll
    for (int s = 32; s >= 1; s >>= 1) m = fmaxf(m, __shfl_xor(m, s, 64));
    const float rs = (m > 0.f) ? (127.0f / m) : 0.f;
    if (l == 0) srow[row] = m * (1.0f / 127.0f);
    uint32_t* xq32 = reinterpret_cast<uint32_t*>(xq + (size_t)row * Kdim);
    #pragma unroll
    for (int j = 0; j < 16; ++j) {
      int a0 = (int)rintf(v[j].x * rs), a1 = (int)rintf(v[j].y * rs);
      int a2 = (int)rintf(v[j].z * rs), a3 = (int)rintf(v[j].w * rs);
      uint32_t p = (uint32_t)(a0 & 255) | ((uint32_t)(a1 & 255) << 8) |
                   ((uint32_t)(a2 & 255) << 16) | ((uint32_t)(a3 & 255) << 24);
      xq32[j * 64 + l] = p;
    }
  } else {
    __shared__ int8_t t[64 * 68];
    const int bid = blockIdx.x - QBLOCKS;
    const int k0 = (bid & 63) * 64;
    const int n0 = (bid >> 6) * 64;
    #pragma unroll
    for (int r = 0; r < 4; ++r) {
      int c  = r * 256 + tid;
      int k  = c >> 4;
      int n4 = (c & 15) * 4;
      float4 v = *reinterpret_cast<const float4*>(w + (size_t)(k0 + k) * Ndim + n0 + n4);
      int s0 = (v.x > 0.f) - (v.x < 0.f);
      int s1 = (v.y > 0.f) - (v.y < 0.f);
      int s2 = (v.z > 0.f) - (v.z < 0.f);
      int s3 = (v.w > 0.f) - (v.w < 0.f);
      uint32_t p = (uint32_t)(s0 & 255) | ((uint32_t)(s1 & 255) << 8) |
                   ((uint32_t)(s2 & 255) << 16) | ((uint32_t)(s3 & 255) << 24);
      *reinterpret_cast<uint32_t*>(&t[k * 68 + n4]) = p;
    }
    __syncthreads();
    const int n  = tid & 63;
    const int ck = (tid >> 6) * 16;
    union { int8_t b[16]; uint4 u; } o;
    #pragma unroll
    for (int j = 0; j < 16; ++j) o.b[j] = t[(ck + j) * 68 + n];
    *reinterpret_cast<uint4*>(wsT + (size_t)(n0 + n) * Kdim + k0 + ck) = o.u;
  }
}

// ---- main GEMM R10: i8 32x32x32 MFMA, 256x256 tile, 8 waves, BKB=64,
//      DEPTH-3 pipeline (3 LDS buffers, 96 KiB): ONE barrier + counted
//      vmcnt(4) per K-tile; stage(t+2) issued MID-COMPUTE (overlaps MFMA)
//      since it writes buffer (t+2)%3 which nobody reads this iteration.
//      (R6/R9 depth-2 ref: 160-170 us, MfmaUtil 32-38%, lockstep 2-barrier.)
//
// vmcnt ledger:
//   prologue: stage(0,b0)+fence+stage(1,b1) -> 8 in flight, tile0's 4 oldest.
//   iter t top: outstanding = {tile t: 4 oldest, tile t+1: 4}.
//     vmcnt(4) retires exactly tile t (in-order). t==NKT-1: vmcnt(0).
//     barrier globalizes (vmcnt is per-wave).
//   during t: issue stage(t+2, (t+2)%3) (t <= NKT-3) -> back to 8.
//   WAR safety: (t+2)%3 == (t-1)%3; tile t-1's ds_reads were consumed by its
//   MFMAs (lgkmcnt) before every wave passed the top-of-t barrier.
// Swizzle closure (4 chunks/row): LDS slot (r,c') holds global chunk
//   c'^(r&3); read col cx=((ks*2+h)^em)*16, em=m&3=row&3 (wm,wn,i*32≡0 mod 4).
__global__ __launch_bounds__(512, 2) void gemm_i8_kernel(const int8_t* __restrict__ A,
                                                         const int8_t* __restrict__ Bt,
                                                         const float* __restrict__ srow,
                                                         const float* __restrict__ bias,
                                                         float* __restrict__ out) {
  __shared__ int8_t sA[3][TILEB];   // 3 x 16 KB
  __shared__ int8_t sB[3][TILEB];   // 3 x 16 KB  -> 96 KiB total, 1 block/CU
  const int tid = threadIdx.x;

  // T1: XCD-chunked bijective block swizzle (nwg = 512, 512 % 8 == 0)
  const int nwg = (Mdim / BM) * (Ndim / BN);      // 512
  const int bid = blockIdx.x;
  const int swz = (bid & 7) * (nwg >> 3) + (bid >> 3);
  const int bm  = swz / (Ndim / BN);
  const int bn  = swz % (Ndim / BN);

  const int lane = tid & 63;
  const int wave = tid >> 6;            // 0..7, arranged 2(M) x 4(N)
  const int wm   = (wave & 1) * 128;    // wave 128x64 output sub-tile origin
  const int wn   = (wave >> 1) * 64;
  const int m    = lane & 31;           // MFMA row/col index
  const int h    = lane >> 5;           // k-half selector
  const int em   = m & 3;               // swizzle key (row&3)

  // staging: 2 slots/thread/matrix (1024 slots x 16B = 16 KB);
  // lane reads the pre-(inverse-)swizzled global chunk
  const int8_t* pA[2];
  const int8_t* pB[2];
  #pragma unroll
  for (int p = 0; p < 2; ++p) {
    int s  = tid + 512 * p;             // slot 0..1023
    int r  = s >> 2;                    // row 0..255 (4 chunks/row)
    int cg = (s & 3) ^ (r & 3);         // inverse-swizzled source chunk
    pA[p] = A  + (size_t)(bm * BM + r) * Kdim + cg * 16;
    pB[p] = Bt + (size_t)(bn * BN + r) * Kdim + cg * 16;
  }

  i32x16 acc[4][2] = {};

  auto stage = [&](int t, int buf) {
    const int k0 = t * BKB;
    int8_t* dA = &sA[0][0] + buf * TILEB;   // address arithmetic, no ptr-array
    int8_t* dB = &sB[0][0] + buf * TILEB;
    #pragma unroll
    for (int p = 0; p < 2; ++p) {
      async_copy16(pA[p] + k0, dA + (tid + 512 * p) * 16);
      async_copy16(pB[p] + k0, dB + (tid + 512 * p) * 16);
    }
  };

  // prologue: tiles 0,1 in flight (8 loads/thread); fence pins issue order
  // so vmcnt(4) == "tile0 landed".
  stage(0, 0);
  asm volatile("" ::: "memory");
  stage(1, 1);

  int cur = 0;
  for (int t = 0; t < NKT; ++t) {
    if (t < NKT - 1) asm volatile("s_waitcnt vmcnt(4)" ::: "memory");
    else             asm volatile("s_waitcnt vmcnt(0)" ::: "memory");
    __builtin_amdgcn_sched_barrier(0);
    __builtin_amdgcn_s_barrier();
    __builtin_amdgcn_sched_barrier(0);

    const int8_t* la = &sA[0][0] + cur * TILEB;
    const int8_t* lb = &sB[0][0] + cur * TILEB;

    // ks = 0 fragment reads
    i32x4 af0[4], bf0[2];
    {
      const int cx = (h ^ em) * 16;
      #pragma unroll
      for (int i = 0; i < 4; ++i)
        af0[i] = *reinterpret_cast<const i32x4*>(&la[(wm + i * 32 + m) * BKB + cx]);
      #pragma unroll
      for (int j = 0; j < 2; ++j)
        bf0[j] = *reinterpret_cast<const i32x4*>(&lb[(wn + j * 32 + m) * BKB + cx]);
    }

    // issue next+2 stage mid-compute: writes buf (cur+2)%3 == (t+2)%3,
    // untouched by any wave this iteration.
    if (t < NKT - 2) {
      int wb = cur + 2; if (wb >= 3) wb -= 3;
      stage(t + 2, wb);
    }

    __builtin_amdgcn_s_setprio(1);
    #pragma unroll
    for (int i = 0; i < 4; ++i)
      #pragma unroll
      for (int j = 0; j < 2; ++j)
        acc[i][j] = __builtin_amdgcn_mfma_i32_32x32x32_i8(af0[i], bf0[j], acc[i][j], 0, 0, 0);
    __builtin_amdgcn_s_setprio(0);

    // ks = 1
    i32x4 af1[4], bf1[2];
    {
      const int cx = ((2 + h) ^ em) * 16;
      #pragma unroll
      for (int i = 0; i < 4; ++i)
        af1[i] = *reinterpret_cast<const i32x4*>(&la[(wm + i * 32 + m) * BKB + cx]);
      #pragma unroll
      for (int j = 0; j < 2; ++j)
        bf1[j] = *reinterpret_cast<const i32x4*>(&lb[(wn + j * 32 + m) * BKB + cx]);
    }
    __builtin_amdgcn_s_setprio(1);
    #pragma unroll
    for (int i = 0; i < 4; ++i)
      #pragma unroll
      for (int j = 0; j < 2; ++j)
        acc[i][j] = __builtin_amdgcn_mfma_i32_32x32x32_i8(af1[i], bf1[j], acc[i][j], 0, 0, 0);
    __builtin_amdgcn_s_setprio(0);

    cur = (cur + 1 == 3) ? 0 : cur + 1;
  }

  // epilogue: C/D 32x32 layout col=lane&31, row=(reg&3)+8*(reg>>2)+4*h
  float bv[2];
  #pragma unroll
  for (int j = 0; j < 2; ++j) bv[j] = bias[bn * BN + wn + j * 32 + m];
  #pragma unroll
  for (int i = 0; i < 4; ++i) {
    const int base_row = bm * BM + wm + i * 32 + 4 * h;
    #pragma unroll
    for (int gg = 0; gg < 4; ++gg) {
      float sv[4];
      #pragma unroll
      for (int rr = 0; rr < 4; ++rr) sv[rr] = srow[base_row + gg * 8 + rr];
      #pragma unroll
      for (int j = 0; j < 2; ++j) {
        const int col = bn * BN + wn + j * 32 + m;
        #pragma unroll
        for (int rr = 0; rr < 4; ++rr) {
          const int reg = gg * 4 + rr;
          out[(size_t)(base_row + gg * 8 + rr) * Ndim + col] =
              (float)acc[i][j][reg] * sv[rr] + bv[j];
        }
      }
    }
  }
}

// ---- fallback (no workspace): fused bf16 convert/binarize staging ----
__global__ __launch_bounds__(256) void gemm_fused_kernel(const float* __restrict__ X,
                                                         const float* __restrict__ W,
                                                         const float* __restrict__ bias,
                                                         float* __restrict__ out) {
  __shared__ __hip_bfloat16 sA[128 * 32];
  __shared__ __hip_bfloat16 sB[128 * 32];
  const int tid  = threadIdx.x;
  const int bn   = blockIdx.x, bm = blockIdx.y;
  const int lane = tid & 63;
  const int wave = tid >> 6;
  const int wm   = (wave & 1) * 64;
  const int wn   = (wave >> 1) * 64;
  const int lr   = lane & 15;
  const int quad = lane >> 4;

  f32x4 acc[4][4] = {};

  for (int k0 = 0; k0 < Kdim; k0 += 32) {
    #pragma unroll
    for (int r = 0; r < 2; ++r) {
      int c = r * 256 + tid;
      int row = c >> 2, col = (c & 3) * 8;
      const float4* p = reinterpret_cast<const float4*>(X + (size_t)(bm * 128 + row) * Kdim + k0 + col);
      float4 v0 = p[0], v1 = p[1];
      float va[8] = {v0.x, v0.y, v0.z, v0.w, v1.x, v1.y, v1.z, v1.w};
      union { __hip_bfloat16 h[8]; uint4 u; } oa;
      #pragma unroll
      for (int u2 = 0; u2 < 8; ++u2) oa.h[u2] = __float2bfloat16(va[u2]);
      *reinterpret_cast<uint4*>(&sA[c * 8]) = oa.u;

      int kl = c >> 4, n8 = (c & 15) * 8;
      const float4* q = reinterpret_cast<const float4*>(W + (size_t)(k0 + kl) * Ndim + bn * 128 + n8);
      float4 w0 = q[0], w1 = q[1];
      float wv[8] = {w0.x, w0.y, w0.z, w0.w, w1.x, w1.y, w1.z, w1.w};
      #pragma unroll
      for (int u2 = 0; u2 < 8; ++u2) {
        float sg = (wv[u2] > 0.f) ? 1.f : ((wv[u2] < 0.f) ? -1.f : 0.f);
        sB[(n8 + u2) * 32 + kl] = __float2bfloat16(sg);
      }
    }
    __syncthreads();

    bf16x8 af[4], bf[4];
    #pragma unroll
    for (int i = 0; i < 4; ++i)
      af[i] = *reinterpret_cast<const bf16x8*>(&sA[(wm + i * 16 + lr) * 32 + quad * 8]);
    #pragma unroll
    for (int j = 0; j < 4; ++j)
      bf[j] = *reinterpret_cast<const bf16x8*>(&sB[(wn + j * 16 + lr) * 32 + quad * 8]);
    #pragma unroll
    for (int i = 0; i < 4; ++i)
      #pragma unroll
      for (int j = 0; j < 4; ++j)
        acc[i][j] = __builtin_amdgcn_mfma_f32_16x16x32_bf16(af[i], bf[j], acc[i][j], 0, 0, 0);
    __syncthreads();
  }

  float bv[4];
  #pragma unroll
  for (int j = 0; j < 4; ++j) bv[j] = bias[bn * 128 + wn + j * 16 + lr];
  #pragma unroll
  for (int i = 0; i < 4; ++i) {
    const size_t rowb = (size_t)(bm * 128 + wm + i * 16 + quad * 4);
    #pragma unroll
    for (int j = 0; j < 4; ++j) {
      const int col = bn * 128 + wn + j * 16 + lr;
      float* o = out + rowb * Ndim + col;
      #pragma unroll
      for (int r = 0; r < 4; ++r)
        o[(size_t)r * Ndim] = acc[i][j][r] + bv[j];
    }
  }
}

extern "C" void kernel_launch(void* const* d_in, const int* in_sizes, int n_in,
                              void* d_out, int out_size, void* d_ws, size_t ws_size,
                              hipStream_t stream) {
  const float* x = (const float*)d_in[0];   // [8192,4096]
  const float* w = (const float*)d_in[1];   // [4096,4096]
  const float* b = (const float*)d_in[2];   // [4096]
  float* out = (float*)d_out;

  const size_t xq_bytes = (size_t)Mdim * Kdim;        // 32 MiB
  const size_t wt_bytes = (size_t)Ndim * Kdim;        // 16 MiB
  const size_t sr_bytes = (size_t)Mdim * sizeof(float);
  const size_t need = xq_bytes + wt_bytes + sr_bytes;

  if (ws_size >= need) {
    int8_t* xq  = (int8_t*)d_ws;
    int8_t* wsT = (int8_t*)((char*)d_ws + xq_bytes);
    float* srow = (float*)((char*)d_ws + xq_bytes + wt_bytes);
    prep_kernel<<<QBLOCKS + SBLOCKS, 256, 0, stream>>>(x, xq, srow, w, wsT);
    gemm_i8_kernel<<<(Mdim / BM) * (Ndim / BN), 512, 0, stream>>>(xq, wsT, srow, b, out);
  } else {
    gemm_fused_kernel<<<dim3(Ndim / 128, Mdim / 128), 256, 0, stream>>>(x, w, b, out);
  }
}

// Round 16
// 422.164 us; speedup vs baseline: 1.0525x; 1.0525x over previous
//
#include <hip/hip_runtime.h>
#include <hip/hip_bf16.h>
#include <cstdint>

typedef __attribute__((ext_vector_type(8))) short bf16x8;
typedef __attribute__((ext_vector_type(4))) float f32x4;
typedef __attribute__((ext_vector_type(4))) int   i32x4;
typedef __attribute__((ext_vector_type(16))) int  i32x16;

static constexpr int Mdim = 8192;
static constexpr int Kdim = 4096;
static constexpr int Ndim = 4096;
static constexpr int BM = 256, BN = 256;   // 256^2 tile (R6-proven)
static constexpr int BKB = 128;            // K-bytes per tile (i8 => 128 k-elems)
static constexpr int NKT = Kdim / BKB;     // 32 K-tiles

static constexpr int QBLOCKS = Mdim / 4;                      // 2048: quant role
static constexpr int SBLOCKS = (Kdim / 64) * (Ndim / 64);     // 4096: sign role

__device__ __forceinline__ void async_copy16(const void* g, void* l) {
  __builtin_amdgcn_global_load_lds(
      (const __attribute__((address_space(1))) void*)g,
      (__attribute__((address_space(3))) void*)l, 16, 0, 0);
}

// ---- fused prepass. R15 change: sign-role WRITE COALESCING — old mapping
//      had 64 lanes write 16B each at stride 4096B (64 partial cache lines
//      per wave); new mapping gives 4 lanes -> one full contiguous 64B line
//      of one row (wave = 16 rows x 64B full lines). Same (row,chunk)
//      coverage, same content. Quant role unchanged.
__global__ __launch_bounds__(256) void prep_kernel(const float* __restrict__ x,
                                                   int8_t* __restrict__ xq,
                                                   float* __restrict__ srow,
                                                   const float* __restrict__ w,
                                                   int8_t* __restrict__ wsT) {
  const int tid = threadIdx.x;
  if (blockIdx.x < QBLOCKS) {
    const int wv  = tid >> 6;
    const int l   = tid & 63;
    const int row = blockIdx.x * 4 + wv;
    const float* xr = x + (size_t)row * Kdim;
    float4 v[16];
    float m = 0.f;
    #pragma unroll
    for (int j = 0; j < 16; ++j) {
      v[j] = *reinterpret_cast<const float4*>(xr + (size_t)(j * 64 + l) * 4);
      m = fmaxf(m, fmaxf(fmaxf(fabsf(v[j].x), fabsf(v[j].y)),
                         fmaxf(fabsf(v[j].z), fabsf(v[j].w))));
    }
    #pragma unroll
    for (int s = 32; s >= 1; s >>= 1) m = fmaxf(m, __shfl_xor(m, s, 64));
    const float rs = (m > 0.f) ? (127.0f / m) : 0.f;
    if (l == 0) srow[row] = m * (1.0f / 127.0f);
    uint32_t* xq32 = reinterpret_cast<uint32_t*>(xq + (size_t)row * Kdim);
    #pragma unroll
    for (int j = 0; j < 16; ++j) {
      int a0 = (int)rintf(v[j].x * rs), a1 = (int)rintf(v[j].y * rs);
      int a2 = (int)rintf(v[j].z * rs), a3 = (int)rintf(v[j].w * rs);
      uint32_t p = (uint32_t)(a0 & 255) | ((uint32_t)(a1 & 255) << 8) |
                   ((uint32_t)(a2 & 255) << 16) | ((uint32_t)(a3 & 255) << 24);
      xq32[j * 64 + l] = p;
    }
  } else {
    __shared__ int8_t t[64 * 68];
    const int bid = blockIdx.x - QBLOCKS;
    const int k0 = (bid & 63) * 64;
    const int n0 = (bid >> 6) * 64;
    #pragma unroll
    for (int r = 0; r < 4; ++r) {
      int c  = r * 256 + tid;
      int k  = c >> 4;
      int n4 = (c & 15) * 4;
      float4 v = *reinterpret_cast<const float4*>(w + (size_t)(k0 + k) * Ndim + n0 + n4);
      int s0 = (v.x > 0.f) - (v.x < 0.f);
      int s1 = (v.y > 0.f) - (v.y < 0.f);
      int s2 = (v.z > 0.f) - (v.z < 0.f);
      int s3 = (v.w > 0.f) - (v.w < 0.f);
      uint32_t p = (uint32_t)(s0 & 255) | ((uint32_t)(s1 & 255) << 8) |
                   ((uint32_t)(s2 & 255) << 16) | ((uint32_t)(s3 & 255) << 24);
      *reinterpret_cast<uint32_t*>(&t[k * 68 + n4]) = p;
    }
    __syncthreads();
    // coalesced output: lane l of wave wv2 -> row n = wv2*16 + (l>>2),
    // chunk ck = (l&3)*16; lanes l, l+1, l+2, l+3 write one full 64B line.
    const int wv2 = tid >> 6;
    const int l   = tid & 63;
    const int n   = wv2 * 16 + (l >> 2);
    const int ck  = (l & 3) * 16;
    union { int8_t b[16]; uint4 u; } o;
    #pragma unroll
    for (int j = 0; j < 16; ++j) o.b[j] = t[(ck + j) * 68 + n];
    *reinterpret_cast<uint4*>(wsT + (size_t)(n0 + n) * Kdim + k0 + ck) = o.u;
  }
}

// ---- main GEMM: REVERTED to R6-proven depth-2 BKB=128 (measured twice:
//      160-172 us, 1.72 PTOPS, MfmaUtil 32-38%, conflicts 1.26e7).
//      R14 lesson: depth-3 @ BKB=64 regressed (184-187 us) — 4-chunk swizzle
//      can't spread 32 lanes (8-way bank conflicts, 3.78e7 = 3x). FROZEN.
//
// vmcnt ledger (R2):
//   prologue: stage(0)+fence+stage(1) -> 16 in flight, tile0's 8 oldest.
//   iter t top: vmcnt(8) retires exactly tile t's 8; barrier globalizes.
//   iter t tail: barrier (all waves done reading buf b), then stage(t+2,b).
//   t >= NKT-2: no stage. t == NKT-1: vmcnt(0).
// Swizzle closure: LDS slot (r,c') holds global chunk c'^(r&7); read uses
//   cx = (k ^ (row&7)); row&7 == m&7 since wm, i*32 are multiples of 8.
__global__ __launch_bounds__(512, 2) void gemm_i8_kernel(const int8_t* __restrict__ A,
                                                         const int8_t* __restrict__ Bt,
                                                         const float* __restrict__ srow,
                                                         const float* __restrict__ bias,
                                                         float* __restrict__ out) {
  __shared__ int8_t sA[2][BM * BKB];   // 2 x 32 KB
  __shared__ int8_t sB[2][BN * BKB];   // 2 x 32 KB   -> 128 KiB total, 1 block/CU
  const int tid = threadIdx.x;

  // T1: XCD-chunked bijective block swizzle (nwg = 512, 512 % 8 == 0)
  const int nwg = (Mdim / BM) * (Ndim / BN);      // 512
  const int bid = blockIdx.x;
  const int swz = (bid & 7) * (nwg >> 3) + (bid >> 3);
  const int bm  = swz / (Ndim / BN);
  const int bn  = swz % (Ndim / BN);

  const int lane = tid & 63;
  const int wave = tid >> 6;            // 0..7, arranged 2(M) x 4(N)
  const int wm   = (wave & 1) * 128;    // wave 128x64 output sub-tile origin
  const int wn   = (wave >> 1) * 64;
  const int m    = lane & 31;           // MFMA row/col index
  const int h    = lane >> 5;           // k-half selector
  const int em   = m & 7;               // swizzle key (wm, i*32 are mult of 8)

  // staging: 4 slots/thread/matrix; lane reads the pre-swizzled global chunk
  const int8_t* pA[4];
  const int8_t* pB[4];
  #pragma unroll
  for (int p = 0; p < 4; ++p) {
    int s  = tid + 512 * p;             // 2048 slots of 16 B = 32 KB
    int r  = s >> 3;                    // row 0..255
    int cg = (s & 7) ^ (r & 7);         // inverse-swizzled source chunk
    pA[p] = A  + (size_t)(bm * BM + r) * Kdim + cg * 16;
    pB[p] = Bt + (size_t)(bn * BN + r) * Kdim + cg * 16;
  }

  i32x16 acc[4][2] = {};

  auto stage = [&](int t, int b) {
    const int k0 = t * BKB;
    #pragma unroll
    for (int p = 0; p < 4; ++p) {
      async_copy16(pA[p] + k0, &sA[b][(tid + 512 * p) * 16]);
      async_copy16(pB[p] + k0, &sB[b][(tid + 512 * p) * 16]);
    }
  };

  // prologue: two K-tiles in flight (16 loads/thread); fence pins issue order
  // so vmcnt(8) == "tile0 landed".
  stage(0, 0);
  asm volatile("" ::: "memory");
  stage(1, 1);

  for (int t = 0; t < NKT; ++t) {
    const int b = t & 1;

    if (t < NKT - 1) asm volatile("s_waitcnt vmcnt(8)" ::: "memory");
    else             asm volatile("s_waitcnt vmcnt(0)" ::: "memory");
    __builtin_amdgcn_sched_barrier(0);
    __builtin_amdgcn_s_barrier();
    __builtin_amdgcn_sched_barrier(0);

    const int8_t* la = &sA[b][0];
    const int8_t* lb = &sB[b][0];
    #pragma unroll
    for (int ks = 0; ks < 4; ++ks) {
      const int cx = ((ks * 2 + h) ^ em) * 16;   // swizzled byte offset in row
      i32x4 af[4], bf[2];
      #pragma unroll
      for (int i = 0; i < 4; ++i)
        af[i] = *reinterpret_cast<const i32x4*>(&la[(wm + i * 32 + m) * BKB + cx]);
      #pragma unroll
      for (int j = 0; j < 2; ++j)
        bf[j] = *reinterpret_cast<const i32x4*>(&lb[(wn + j * 32 + m) * BKB + cx]);
      __builtin_amdgcn_s_setprio(1);
      #pragma unroll
      for (int i = 0; i < 4; ++i)
        #pragma unroll
        for (int j = 0; j < 2; ++j)
          acc[i][j] = __builtin_amdgcn_mfma_i32_32x32x32_i8(af[i], bf[j], acc[i][j], 0, 0, 0);
      __builtin_amdgcn_s_setprio(0);
    }

    // all waves done reading dbuf[b] before anyone overwrites it
    __builtin_amdgcn_sched_barrier(0);
    __builtin_amdgcn_s_barrier();
    __builtin_amdgcn_sched_barrier(0);
    if (t < NKT - 2) stage(t + 2, b);
  }

  // epilogue: C/D 32x32 layout col=lane&31, row=(reg&3)+8*(reg>>2)+4*h
  float bv[2];
  #pragma unroll
  for (int j = 0; j < 2; ++j) bv[j] = bias[bn * BN + wn + j * 32 + m];
  #pragma unroll
  for (int i = 0; i < 4; ++i) {
    const int base_row = bm * BM + wm + i * 32 + 4 * h;
    #pragma unroll
    for (int gg = 0; gg < 4; ++gg) {
      float sv[4];
      #pragma unroll
      for (int rr = 0; rr < 4; ++rr) sv[rr] = srow[base_row + gg * 8 + rr];
      #pragma unroll
      for (int j = 0; j < 2; ++j) {
        const int col = bn * BN + wn + j * 32 + m;
        #pragma unroll
        for (int rr = 0; rr < 4; ++rr) {
          const int reg = gg * 4 + rr;
          out[(size_t)(base_row + gg * 8 + rr) * Ndim + col] =
              (float)acc[i][j][reg] * sv[rr] + bv[j];
        }
      }
    }
  }
}

// ---- fallback (no workspace): fused bf16 convert/binarize staging ----
__global__ __launch_bounds__(256) void gemm_fused_kernel(const float* __restrict__ X,
                                                         const float* __restrict__ W,
                                                         const float* __restrict__ bias,
                                                         float* __restrict__ out) {
  __shared__ __hip_bfloat16 sA[128 * 32];
  __shared__ __hip_bfloat16 sB[128 * 32];
  const int tid  = threadIdx.x;
  const int bn   = blockIdx.x, bm = blockIdx.y;
  const int lane = tid & 63;
  const int wave = tid >> 6;
  const int wm   = (wave & 1) * 64;
  const int wn   = (wave >> 1) * 64;
  const int lr   = lane & 15;
  const int quad = lane >> 4;

  f32x4 acc[4][4] = {};

  for (int k0 = 0; k0 < Kdim; k0 += 32) {
    #pragma unroll
    for (int r = 0; r < 2; ++r) {
      int c = r * 256 + tid;
      int row = c >> 2, col = (c & 3) * 8;
      const float4* p = reinterpret_cast<const float4*>(X + (size_t)(bm * 128 + row) * Kdim + k0 + col);
      float4 v0 = p[0], v1 = p[1];
      float va[8] = {v0.x, v0.y, v0.z, v0.w, v1.x, v1.y, v1.z, v1.w};
      union { __hip_bfloat16 h[8]; uint4 u; } oa;
      #pragma unroll
      for (int u2 = 0; u2 < 8; ++u2) oa.h[u2] = __float2bfloat16(va[u2]);
      *reinterpret_cast<uint4*>(&sA[c * 8]) = oa.u;

      int kl = c >> 4, n8 = (c & 15) * 8;
      const float4* q = reinterpret_cast<const float4*>(W + (size_t)(k0 + kl) * Ndim + bn * 128 + n8);
      float4 w0 = q[0], w1 = q[1];
      float wv[8] = {w0.x, w0.y, w0.z, w0.w, w1.x, w1.y, w1.z, w1.w};
      #pragma unroll
      for (int u2 = 0; u2 < 8; ++u2) {
        float sg = (wv[u2] > 0.f) ? 1.f : ((wv[u2] < 0.f) ? -1.f : 0.f);
        sB[(n8 + u2) * 32 + kl] = __float2bfloat16(sg);
      }
    }
    __syncthreads();

    bf16x8 af[4], bf[4];
    #pragma unroll
    for (int i = 0; i < 4; ++i)
      af[i] = *reinterpret_cast<const bf16x8*>(&sA[(wm + i * 16 + lr) * 32 + quad * 8]);
    #pragma unroll
    for (int j = 0; j < 4; ++j)
      bf[j] = *reinterpret_cast<const bf16x8*>(&sB[(wn + j * 16 + lr) * 32 + quad * 8]);
    #pragma unroll
    for (int i = 0; i < 4; ++i)
      #pragma unroll
      for (int j = 0; j < 4; ++j)
        acc[i][j] = __builtin_amdgcn_mfma_f32_16x16x32_bf16(af[i], bf[j], acc[i][j], 0, 0, 0);
    __syncthreads();
  }

  float bv[4];
  #pragma unroll
  for (int j = 0; j < 4; ++j) bv[j] = bias[bn * 128 + wn + j * 16 + lr];
  #pragma unroll
  for (int i = 0; i < 4; ++i) {
    const size_t rowb = (size_t)(bm * 128 + wm + i * 16 + quad * 4);
    #pragma unroll
    for (int j = 0; j < 4; ++j) {
      const int col = bn * 128 + wn + j * 16 + lr;
      float* o = out + rowb * Ndim + col;
      #pragma unroll
      for (int r = 0; r < 4; ++r)
        o[(size_t)r * Ndim] = acc[i][j][r] + bv[j];
    }
  }
}

extern "C" void kernel_launch(void* const* d_in, const int* in_sizes, int n_in,
                              void* d_out, int out_size, void* d_ws, size_t ws_size,
                              hipStream_t stream) {
  const float* x = (const float*)d_in[0];   // [8192,4096]
  const float* w = (const float*)d_in[1];   // [4096,4096]
  const float* b = (const float*)d_in[2];   // [4096]
  float* out = (float*)d_out;

  const size_t xq_bytes = (size_t)Mdim * Kdim;        // 32 MiB
  const size_t wt_bytes = (size_t)Ndim * Kdim;        // 16 MiB
  const size_t sr_bytes = (size_t)Mdim * sizeof(float);
  const size_t need = xq_bytes + wt_bytes + sr_bytes;

  if (ws_size >= need) {
    int8_t* xq  = (int8_t*)d_ws;
    int8_t* wsT = (int8_t*)((char*)d_ws + xq_bytes);
    float* srow = (float*)((char*)d_ws + xq_bytes + wt_bytes);
    prep_kernel<<<QBLOCKS + SBLOCKS, 256, 0, stream>>>(x, xq, srow, w, wsT);
    gemm_i8_kernel<<<(Mdim / BM) * (Ndim / BN), 512, 0, stream>>>(xq, wsT, srow, b, out);
  } else {
    gemm_fused_kernel<<<dim3(Ndim / 128, Mdim / 128), 256, 0, stream>>>(x, w, b, out);
  }
}